// Round 2
// baseline (1290.159 us; speedup 1.0000x reference)
//
#include <hip/hip_runtime.h>
#include <hip/hip_bf16.h>
#include <stdint.h>

typedef unsigned short u16;
typedef unsigned int   u32;
typedef __attribute__((ext_vector_type(8))) short bf16x8;
typedef __attribute__((ext_vector_type(4))) float f32x4;

#define GLAS  __attribute__((address_space(1)))
#define LDSAS __attribute__((address_space(3)))

// async global->LDS, 16B per lane. LDS dest is wave-uniform base + lane*16.
__device__ __forceinline__ void gl_lds16(const void* g, void* l) {
    __builtin_amdgcn_global_load_lds((const GLAS u32*)(uintptr_t)g,
                                     (LDSAS u32*)(u32)(uintptr_t)l, 16, 0, 0);
}

// RNE fp32->bf16
__device__ __forceinline__ u16 f2bf_rne(float f) {
    u32 u = __float_as_uint(f);
    u32 r = u + 0x7fffu + ((u >> 16) & 1u);
    return (u16)(r >> 16);
}
// packed pair (v_cvt_pk_bf16_f32 on gfx950), low16 = a
__device__ __forceinline__ u32 pk_bf2(float a, float b) {
    __hip_bfloat162 h = __float22bfloat162_rn(float2{a, b});
    u32 u; __builtin_memcpy(&u, &h, 4);
    return u;
}
__device__ __forceinline__ float bfbits_lo(u32 p) { return __uint_as_float(p << 16); }
__device__ __forceinline__ float bfbits_hi(u32 p) { return __uint_as_float(p & 0xffff0000u); }

__device__ __forceinline__ void unpack8(uint4 u, float* f) {
    f[0] = bfbits_lo(u.x); f[1] = bfbits_hi(u.x);
    f[2] = bfbits_lo(u.y); f[3] = bfbits_hi(u.y);
    f[4] = bfbits_lo(u.z); f[5] = bfbits_hi(u.z);
    f[6] = bfbits_lo(u.w); f[7] = bfbits_hi(u.w);
}

// ---------------- weight transpose + convert: WT[n][k] = bf16(W[k][n]) ----------------
struct WtArgs { const float* W[4]; u16* WT[4]; };

__global__ __launch_bounds__(256) void wtrans(WtArgs a) {
    const int z = blockIdx.z;
    const float* __restrict__ W = a.W[z];
    u16* __restrict__ WT = a.WT[z];
    __shared__ float tile[64][65];
    const int n0 = blockIdx.x * 64, k0 = blockIdx.y * 64;
    const int tid = threadIdx.x;
    const int r = tid >> 6, c = tid & 63;
    #pragma unroll
    for (int p = 0; p < 16; ++p) {
        const int row = p * 4 + r;
        tile[row][c] = W[(size_t)(k0 + row) * 1024 + n0 + c];
    }
    __syncthreads();
    #pragma unroll
    for (int p = 0; p < 16; ++p) {
        const int row = p * 4 + r;   // n index within tile
        WT[(size_t)(n0 + row) * 1024 + k0 + c] = f2bf_rne(tile[c][row]);
    }
}

// ---------------- fp32 -> bf16 streaming convert ----------------
__global__ __launch_bounds__(256) void cvt_bf16(const float* __restrict__ src,
                                                u16* __restrict__ dst, int n8) {
    const int stride = gridDim.x * 256;
    for (int i = blockIdx.x * 256 + threadIdx.x; i < n8; i += stride) {
        const float4* s = (const float4*)(src + (size_t)i * 8);
        float4 x = s[0], y = s[1];
        uint4 o;
        o.x = pk_bf2(x.x, x.y); o.y = pk_bf2(x.z, x.w);
        o.z = pk_bf2(y.x, y.y); o.w = pk_bf2(y.z, y.w);
        *(uint4*)(dst + (size_t)i * 8) = o;
    }
}

// ---------------- 256x256 8-phase GEMM: C[m][n] = sum_k A[m][k]*BT[n][k] + bias[n] ---
// 8 waves (2M x 4N), BK=64, LDS = 2 buf x {A.h0,A.h1,B.h0,B.h1} x 16KB = 128KB.
// st_16x32 swizzle applied as pre-swizzled global source + XOR on the ds_read address.
// ALL in-loop LDS reads and barriers are inline asm: the compiler's waitcnt inserter
// must not see any DS read that aliases the in-flight global_load_lds DMAs, or it
// inserts vmcnt(0) drains every phase (round-1 failure: 15% MfmaUtil, all pipes idle).
struct G8Args { const u16* A[3]; const u16* BT[3]; const float* bias[3]; void* C[3]; };

__device__ __forceinline__ void stage_half(const u16* __restrict__ src, int ldk,
                                           int grow0, int k0, u16* half_,
                                           int wave, int lane) {
    // dest byte P = (wave*2+i)*1024 + lane*16 ; logical = P ^ ((P>>9&1)<<5)
    const int col = ((lane & 7) * 8) ^ ((lane & 32) ? 16 : 0);   // u16 units
    const int rsub = lane >> 3;
    #pragma unroll
    for (int i = 0; i < 2; ++i) {
        const int row = wave * 16 + i * 8 + rsub;                // 0..127
        gl_lds16(src + (size_t)(grow0 + row) * ldk + (k0 + col),
                 half_ + (wave * 2 + i) * 512);
    }
}

// opaque LDS 16B read (compiler cannot see it as a DS op -> no auto vmcnt drain)
__device__ __forceinline__ bf16x8 ds_ld128(u32 addr) {
    bf16x8 r;
    asm volatile("ds_read_b128 %0, %1" : "=v"(r) : "v"(addr));
    return r;
}

__device__ __forceinline__ u32 frag_addr(u32 base, int row, int kk, int lane) {
    int off = row * 64 + kk * 32 + (lane >> 4) * 8;              // u16 units
    off ^= (row & 4) << 2;                                       // st_16x32 read-side XOR
    return base + (u32)(off * 2);
}

#define SBAR  __builtin_amdgcn_sched_barrier(0)
#define WBAR  asm volatile("s_barrier" ::: "memory")
#define LGKM0 asm volatile("s_waitcnt lgkmcnt(0)" ::: "memory")
#define PHASE_MID() do { SBAR; WBAR; LGKM0; SBAR; __builtin_amdgcn_s_setprio(1); } while (0)
#define PHASE_END() do { __builtin_amdgcn_s_setprio(0); SBAR; WBAR; } while (0)

template<bool OUT_F32>
__global__ __launch_bounds__(512, 2)
void gemm8(G8Args ga, int M, int N, int K) {
    __shared__ u16 lds[2][4][8192];   // [buf][A.h0,A.h1,B.h0,B.h1][16KB]
    const int bid = blockIdx.x;
    const int z = bid >> 9;                 // 512 blocks per matrix
    const int r = bid & 511;
    const int xcd = r & 7, s = r >> 3;      // bijective XCD swizzle (512 % 8 == 0)
    const int m0 = (xcd * 16 + (s >> 2)) * 256;
    const int n0 = (s & 3) * 256;
    const u16* __restrict__ A  = ga.A[z];
    const u16* __restrict__ BT = ga.BT[z];
    const int tid = threadIdx.x, lane = tid & 63, wave = tid >> 6;
    const int wmi = wave >> 2, wni = wave & 3;
    const int l15 = lane & 15;
    const int br0 = (wni & 1) * 64;
    const int NT = K >> 6;                  // BK = 64; NT even, >= 2

    f32x4 acc[8][4] = {};
    bf16x8 a[4][2], b01[2][2], b23[2][2];

    // prologue: tile0 all 4 halves + tile1 A halves (acts as tile -1's P3)
    stage_half(A,  K, m0,       0, &lds[0][0][0], wave, lane);
    stage_half(A,  K, m0 + 128, 0, &lds[0][1][0], wave, lane);
    stage_half(BT, K, n0,       0, &lds[0][2][0], wave, lane);
    stage_half(BT, K, n0 + 128, 0, &lds[0][3][0], wave, lane);
    if (NT > 1) {
        stage_half(A, K, m0,       64, &lds[1][0][0], wave, lane);
        stage_half(A, K, m0 + 128, 64, &lds[1][1][0], wave, lane);
        asm volatile("s_waitcnt vmcnt(4)" ::: "memory");
    } else {
        asm volatile("s_waitcnt vmcnt(0)" ::: "memory");
    }
    SBAR; WBAR;

    auto quad = [&](int mb, bf16x8 (&bb)[2][2], int nb) {
        #pragma unroll
        for (int kk = 0; kk < 2; ++kk)
            #pragma unroll
            for (int mf = 0; mf < 4; ++mf)
                #pragma unroll
                for (int nf = 0; nf < 2; ++nf)
                    acc[mb + mf][nb + nf] = __builtin_amdgcn_mfma_f32_16x16x32_bf16(
                        a[mf][kk], bb[nf][kk], acc[mb + mf][nb + nf], 0, 0, 0);
    };

    auto ktile = [&](int t, int buf) {
        const u32 Ab = (u32)(uintptr_t)&lds[buf][wmi][0];
        const u32 Bb = (u32)(uintptr_t)&lds[buf][2 + (wni >> 1)][0];
        // ---- P0: a[0-3] + b[0-1]; stage (t+1).B.h0
        #pragma unroll
        for (int mf = 0; mf < 4; ++mf) {
            a[mf][0] = ds_ld128(frag_addr(Ab, mf * 16 + l15, 0, lane));
            a[mf][1] = ds_ld128(frag_addr(Ab, mf * 16 + l15, 1, lane));
        }
        #pragma unroll
        for (int nf = 0; nf < 2; ++nf) {
            b01[nf][0] = ds_ld128(frag_addr(Bb, br0 + nf * 16 + l15, 0, lane));
            b01[nf][1] = ds_ld128(frag_addr(Bb, br0 + nf * 16 + l15, 1, lane));
        }
        if (t + 1 < NT) stage_half(BT, K, n0, (t + 1) * 64, &lds[buf ^ 1][2][0], wave, lane);
        PHASE_MID();
        quad(0, b01, 0);
        PHASE_END();
        // ---- P1: b[2-3]; stage (t+1).B.h1
        #pragma unroll
        for (int nf = 0; nf < 2; ++nf) {
            b23[nf][0] = ds_ld128(frag_addr(Bb, br0 + (2 + nf) * 16 + l15, 0, lane));
            b23[nf][1] = ds_ld128(frag_addr(Bb, br0 + (2 + nf) * 16 + l15, 1, lane));
        }
        if (t + 1 < NT) stage_half(BT, K, n0 + 128, (t + 1) * 64, &lds[buf ^ 1][3][0], wave, lane);
        PHASE_MID();
        quad(0, b23, 2);
        PHASE_END();
        // ---- P2: a[4-7] (reads of this tile's LDS end here)
        #pragma unroll
        for (int mf = 0; mf < 4; ++mf) {
            a[mf][0] = ds_ld128(frag_addr(Ab, (4 + mf) * 16 + l15, 0, lane));
            a[mf][1] = ds_ld128(frag_addr(Ab, (4 + mf) * 16 + l15, 1, lane));
        }
        PHASE_MID();
        quad(4, b23, 2);
        PHASE_END();
        // ---- P3: no LDS reads; stage (t+2).A into THIS buf (now read-free);
        //          counted vmcnt: keep the just-issued A loads in flight.
        if (t + 2 < NT) {
            stage_half(A, K, m0,       (t + 2) * 64, &lds[buf][0][0], wave, lane);
            stage_half(A, K, m0 + 128, (t + 2) * 64, &lds[buf][1][0], wave, lane);
        }
        SBAR; WBAR; SBAR;
        __builtin_amdgcn_s_setprio(1);
        quad(4, b01, 0);
        __builtin_amdgcn_s_setprio(0);
        SBAR;
        if (t + 2 < NT) asm volatile("s_waitcnt vmcnt(4)" ::: "memory");
        else            asm volatile("s_waitcnt vmcnt(0)" ::: "memory");
        SBAR; WBAR;
    };

    for (int t = 0; t < NT; t += 2) { ktile(t, 0); ktile(t + 1, 1); }

    // ---- epilogue: C/D layout col=lane&15, row=(lane>>4)*4+rr
    const float* __restrict__ bias = ga.bias[z];
    const int r0 = m0 + wmi * 128 + (lane >> 4) * 4;
    const int c0 = n0 + wni * 64 + l15;
    #pragma unroll
    for (int nf = 0; nf < 4; ++nf) {
        const int col = c0 + nf * 16;
        const float bv = bias[col];
        #pragma unroll
        for (int mf = 0; mf < 8; ++mf) {
            #pragma unroll
            for (int rr = 0; rr < 4; ++rr) {
                const int row = r0 + mf * 16 + rr;
                const float v2 = acc[mf][nf][rr] + bv;
                if constexpr (OUT_F32) ((float*)ga.C[z])[(size_t)row * N + col] = v2;
                else                   ((u16*)ga.C[z])[(size_t)row * N + col] = f2bf_rne(v2);
            }
        }
    }
    (void)M;
}

// ---------------- attention over head axis, per (b, g=l/16) tile ----------------
// Q[b,l,h,d] = QL[b, h*256+g, t*64+d], l = g*16+t   (faithful to reference reshape)
__global__ __launch_bounds__(256, 2)
void attn(const u16* __restrict__ QL, const u16* __restrict__ KL, const u16* __restrict__ VL,
          u16* __restrict__ CTX, float* __restrict__ WOUT) {
    __shared__ u16 Ks[16 * 1024];
    __shared__ u16 Vs[16 * 1024];
    const int bg = blockIdx.x;
    const int b = bg >> 8, g = bg & 255;
    const int tid = threadIdx.x, lane = tid & 63, wave = tid >> 6;
    const size_t boff = (size_t)b * (4096 * 1024);

    for (int it = 0; it < 8; ++it) {
        const int c = it * 4 + wave;           // 0..31
        const int row = c >> 1, half = c & 1;
        const size_t gidx = boff + (size_t)(row * 256 + g) * 1024 + half * 512 + lane * 8;
        gl_lds16(KL + gidx, &Ks[c * 512]);
        gl_lds16(VL + gidx, &Vs[c * 512]);
    }
    __syncthreads();

    const int t = tid >> 4, h = tid & 15;
    float qf[64];
    const u16* qp = QL + boff + (size_t)(h * 256 + g) * 1024 + t * 64;
    #pragma unroll
    for (int c8 = 0; c8 < 8; ++c8) {
        uint4 u = *(const uint4*)(qp + c8 * 8);
        unpack8(u, &qf[c8 * 8]);
    }
    float s[16];
    #pragma unroll 1
    for (int j = 0; j < 16; ++j) {
        const u16* kp = &Ks[j * 1024 + t * 64];
        float a = 0.f;
        #pragma unroll
        for (int c8 = 0; c8 < 8; ++c8) {
            uint4 u = *(const uint4*)(kp + c8 * 8);
            float kf[8]; unpack8(u, kf);
            #pragma unroll
            for (int d = 0; d < 8; ++d) a = fmaf(qf[c8 * 8 + d], kf[d], a);
        }
        s[j] = a * 0.125f;
    }
    float mx = s[0];
    #pragma unroll
    for (int j = 1; j < 16; ++j) mx = fmaxf(mx, s[j]);
    float w[16], sum = 0.f;
    #pragma unroll
    for (int j = 0; j < 16; ++j) { w[j] = __expf(s[j] - mx); sum += w[j]; }
    const float inv = 1.f / sum;
    #pragma unroll
    for (int j = 0; j < 16; ++j) w[j] *= inv;
    {
        float4* wp = (float4*)(WOUT + ((size_t)((b * 4096 + g * 16 + t) * 16 + h) * 16));
        wp[0] = float4{w[0],  w[1],  w[2],  w[3]};
        wp[1] = float4{w[4],  w[5],  w[6],  w[7]};
        wp[2] = float4{w[8],  w[9],  w[10], w[11]};
        wp[3] = float4{w[12], w[13], w[14], w[15]};
    }
    float cx[64];
    #pragma unroll
    for (int d = 0; d < 64; ++d) cx[d] = 0.f;
    #pragma unroll 1
    for (int j = 0; j < 16; ++j) {
        const u16* vp = &Vs[j * 1024 + t * 64];
        const float wj = w[j];
        #pragma unroll
        for (int c8 = 0; c8 < 8; ++c8) {
            uint4 u = *(const uint4*)(vp + c8 * 8);
            float vf[8]; unpack8(u, vf);
            #pragma unroll
            for (int d = 0; d < 8; ++d) cx[c8 * 8 + d] = fmaf(wj, vf[d], cx[c8 * 8 + d]);
        }
    }
    u16* cp = CTX + boff + (size_t)(h * 256 + g) * 1024 + t * 64;
    #pragma unroll
    for (int c8 = 0; c8 < 8; ++c8) {
        uint4 o;
        o.x = pk_bf2(cx[c8 * 8 + 0], cx[c8 * 8 + 1]);
        o.y = pk_bf2(cx[c8 * 8 + 2], cx[c8 * 8 + 3]);
        o.z = pk_bf2(cx[c8 * 8 + 4], cx[c8 * 8 + 5]);
        o.w = pk_bf2(cx[c8 * 8 + 6], cx[c8 * 8 + 7]);
        *(uint4*)(cp + c8 * 8) = o;
    }
}

// ---------------- host ----------------
extern "C" void kernel_launch(void* const* d_in, const int* in_sizes, int n_in,
                              void* d_out, int out_size, void* d_ws, size_t ws_size,
                              hipStream_t stream) {
    const float* q  = (const float*)d_in[0];
    const float* k  = (const float*)d_in[1];
    const float* v  = (const float*)d_in[2];
    const float* Wq = (const float*)d_in[3];
    const float* bq = (const float*)d_in[4];
    const float* Wk = (const float*)d_in[5];
    const float* bk = (const float*)d_in[6];
    const float* Wv = (const float*)d_in[7];
    const float* bv = (const float*)d_in[8];
    const float* Wo = (const float*)d_in[9];
    const float* bo = (const float*)d_in[10];

    const int M = 32768, D = 1024;
    const size_t MD = (size_t)M * D;
    const int n8 = (int)(MD / 8);

    u16* WT0 = (u16*)d_ws;
    u16* WT1 = WT0 + 1048576;
    u16* WT2 = WT1 + 1048576;
    u16* WT3 = WT2 + 1048576;
    u16* big0 = WT3 + 1048576;

    float* out  = (float*)d_out;
    float* wout = out + MD;

    WtArgs wa{{Wq, Wk, Wv, Wo}, {WT0, WT1, WT2, WT3}};
    wtrans<<<dim3(16, 16, 4), 256, 0, stream>>>(wa);

    const size_t needBig = 2ull * (4ull * 1048576 + 6ull * MD);   // ~392 MiB
    if (ws_size >= needBig) {
        // fused path: 3 bf16 input copies live at once, single QKV GEMM launch
        u16* QB = big0;      u16* KB = QB + MD;  u16* VB = KB + MD;
        u16* QL = VB + MD;   u16* KL = QL + MD;  u16* VL = KL + MD;
        u16* CTX = QB;       // QB dead after GEMM1
        cvt_bf16<<<dim3(2048), 256, 0, stream>>>(q, QB, n8);
        cvt_bf16<<<dim3(2048), 256, 0, stream>>>(k, KB, n8);
        cvt_bf16<<<dim3(2048), 256, 0, stream>>>(v, VB, n8);
        G8Args g1{{QB, KB, VB}, {WT0, WT1, WT2}, {bq, bk, bv}, {QL, KL, VL}};
        gemm8<false><<<dim3(3 * 512), 512, 0, stream>>>(g1, M, D, D);
        attn<<<dim3(2048), 256, 0, stream>>>(QL, KL, VL, CTX, wout);
        G8Args g2{{CTX, CTX, CTX}, {WT3, WT3, WT3}, {bo, bo, bo}, {out, out, out}};
        gemm8<true><<<dim3(512), 512, 0, stream>>>(g2, M, D, D);
    } else {
        // conservative path: one shared bf16 A-buffer (264 MiB footprint)
        u16* AB = big0;
        u16* QL = AB + MD;   u16* KL = QL + MD;  u16* VL = KL + MD;
        u16* CTX = AB;       // AB dead after the three GEMM1s
        const float* src[3]  = {q, k, v};
        const float* bia[3]  = {bq, bk, bv};
        u16* wt[3]           = {WT0, WT1, WT2};
        u16* dst[3]          = {QL, KL, VL};
        for (int i = 0; i < 3; ++i) {
            cvt_bf16<<<dim3(2048), 256, 0, stream>>>(src[i], AB, n8);
            G8Args g1{{AB, AB, AB}, {wt[i], wt[i], wt[i]}, {bia[i], bia[i], bia[i]},
                      {dst[i], dst[i], dst[i]}};
            gemm8<false><<<dim3(512), 512, 0, stream>>>(g1, M, D, D);
        }
        attn<<<dim3(2048), 256, 0, stream>>>(QL, KL, VL, CTX, wout);
        G8Args g2{{CTX, CTX, CTX}, {WT3, WT3, WT3}, {bo, bo, bo}, {out, out, out}};
        gemm8<true><<<dim3(512), 512, 0, stream>>>(g2, M, D, D);
    }
}

// Round 3
// 905.817 us; speedup vs baseline: 1.4243x; 1.4243x over previous
//
#include <hip/hip_runtime.h>
#include <hip/hip_bf16.h>
#include <stdint.h>

typedef unsigned short u16;
typedef unsigned int   u32;
typedef __attribute__((ext_vector_type(8))) short bf16x8;
typedef __attribute__((ext_vector_type(4))) float f32x4;

#define GLAS  __attribute__((address_space(1)))
#define LDSAS __attribute__((address_space(3)))

// async global->LDS, 16B per lane. LDS dest is wave-uniform base + lane*16.
__device__ __forceinline__ void gl_lds16(const void* g, void* l) {
    __builtin_amdgcn_global_load_lds((const GLAS u32*)(uintptr_t)g,
                                     (LDSAS u32*)(u32)(uintptr_t)l, 16, 0, 0);
}

// RNE fp32->bf16
__device__ __forceinline__ u16 f2bf_rne(float f) {
    u32 u = __float_as_uint(f);
    u32 r = u + 0x7fffu + ((u >> 16) & 1u);
    return (u16)(r >> 16);
}
// packed pair (v_cvt_pk_bf16_f32 on gfx950), low16 = a
__device__ __forceinline__ u32 pk_bf2(float a, float b) {
    __hip_bfloat162 h = __float22bfloat162_rn(float2{a, b});
    u32 u; __builtin_memcpy(&u, &h, 4);
    return u;
}
__device__ __forceinline__ float bfbits_lo(u32 p) { return __uint_as_float(p << 16); }
__device__ __forceinline__ float bfbits_hi(u32 p) { return __uint_as_float(p & 0xffff0000u); }

__device__ __forceinline__ void unpack8(uint4 u, float* f) {
    f[0] = bfbits_lo(u.x); f[1] = bfbits_hi(u.x);
    f[2] = bfbits_lo(u.y); f[3] = bfbits_hi(u.y);
    f[4] = bfbits_lo(u.z); f[5] = bfbits_hi(u.z);
    f[6] = bfbits_lo(u.w); f[7] = bfbits_hi(u.w);
}

// ---------------- weight transpose + convert: WT[n][k] = bf16(W[k][n]) ----------------
struct WtArgs { const float* W[4]; u16* WT[4]; };

__global__ __launch_bounds__(256) void wtrans(WtArgs a) {
    const int z = blockIdx.z;
    const float* __restrict__ W = a.W[z];
    u16* __restrict__ WT = a.WT[z];
    __shared__ float tile[64][65];
    const int n0 = blockIdx.x * 64, k0 = blockIdx.y * 64;
    const int tid = threadIdx.x;
    const int r = tid >> 6, c = tid & 63;
    #pragma unroll
    for (int p = 0; p < 16; ++p) {
        const int row = p * 4 + r;
        tile[row][c] = W[(size_t)(k0 + row) * 1024 + n0 + c];
    }
    __syncthreads();
    #pragma unroll
    for (int p = 0; p < 16; ++p) {
        const int row = p * 4 + r;   // n index within tile
        WT[(size_t)(n0 + row) * 1024 + k0 + c] = f2bf_rne(tile[c][row]);
    }
}

// ---------------- fp32 -> bf16 streaming convert (up to 3 tensors per launch) --------
struct CvtArgs { const float* src[3]; u16* dst[3]; };

__global__ __launch_bounds__(256) void cvt3(CvtArgs a, int n8) {
    const int z = blockIdx.y;
    const float* __restrict__ src = a.src[z];
    u16* __restrict__ dst = a.dst[z];
    const int stride = gridDim.x * 256;
    for (int i = blockIdx.x * 256 + threadIdx.x; i < n8; i += stride) {
        const float4* s = (const float4*)(src + (size_t)i * 8);
        float4 x = s[0], y = s[1];
        uint4 o;
        o.x = pk_bf2(x.x, x.y); o.y = pk_bf2(x.z, x.w);
        o.z = pk_bf2(y.x, y.y); o.w = pk_bf2(y.z, y.w);
        *(uint4*)(dst + (size_t)i * 8) = o;
    }
}

// ---------------- GEMM: C[m][n] = sum_k A[m][k] * BT[n][k] + bias[n] ----------------
// Proven m97-style 128x128 tile, BK=32, bf16 A and B both staged via global_load_lds
// width-16, 16 KB LDS (-> ~3 blocks/CU so barrier drains overlap across blocks).
// Flat 1D grid, XCD-aware decode: 2048 blocks per z (M/128=256 x N/128=8).
struct GemmArgs { const u16* A[3]; const u16* BT[3]; const float* bias[3]; void* C[3]; };

template<bool OUT_F32>
__global__ __launch_bounds__(256, 2)
void gemm_bt(GemmArgs ga, int M, int N, int K) {
    __shared__ u16 As[128 * 32];
    __shared__ u16 Bs[128 * 32];
    const int L = blockIdx.x;
    const int z = L >> 11;               // 2048 blocks per z
    const int r = L & 2047;
    const int xcd = r & 7;
    const int slot = r >> 3;             // 0..255 within partition
    const int m0 = (xcd * 32 + (slot >> 3)) * 128;
    const int n0 = (slot & 7) * 128;

    const u16*   __restrict__ A    = ga.A[z];
    const u16*   __restrict__ BT   = ga.BT[z];
    const float* __restrict__ bias = ga.bias[z];
    const int tid = threadIdx.x;
    const int lane = tid & 63;
    const int wave = tid >> 6;

    f32x4 acc[4][4] = {};

    const int srow = lane >> 2;        // row within 16-row chunk
    const int scol = (lane & 3) * 8;   // col within 32 (8 bf16 = 16B)

    for (int k0 = 0; k0 < K; k0 += 32) {
        // ---- stage A and B tiles (128x32 bf16 each) via async global->LDS
        #pragma unroll
        for (int cc = 0; cc < 2; ++cc) {
            const int chunk = cc * 4 + wave;
            gl_lds16(A  + (size_t)(m0 + chunk * 16 + srow) * K + (k0 + scol),
                     &As[chunk * 512]);
            gl_lds16(BT + (size_t)(n0 + chunk * 16 + srow) * K + (k0 + scol),
                     &Bs[chunk * 512]);
        }
        __syncthreads();

        // ---- fragments + MFMA
        const int wm = (wave >> 1) * 64;
        const int wn = (wave & 1) * 64;
        const int fr = lane & 15;
        const int fk = (lane >> 4) * 8;
        bf16x8 af[4], bfr[4];
        #pragma unroll
        for (int i = 0; i < 4; ++i) af[i]  = *(const bf16x8*)&As[(wm + i * 16 + fr) * 32 + fk];
        #pragma unroll
        for (int j = 0; j < 4; ++j) bfr[j] = *(const bf16x8*)&Bs[(wn + j * 16 + fr) * 32 + fk];
        #pragma unroll
        for (int i = 0; i < 4; ++i)
            #pragma unroll
            for (int j = 0; j < 4; ++j)
                acc[i][j] = __builtin_amdgcn_mfma_f32_16x16x32_bf16(af[i], bfr[j], acc[i][j], 0, 0, 0);
        __syncthreads();
    }

    // ---- epilogue: C/D layout col=lane&15, row=(lane>>4)*4+rr
    const int wm = (wave >> 1) * 64;
    const int wn = (wave & 1) * 64;
    const int r0 = m0 + wm + (lane >> 4) * 4;
    const int c0 = n0 + wn + (lane & 15);
    #pragma unroll
    for (int j = 0; j < 4; ++j) {
        const int col = c0 + j * 16;
        const float bv = bias[col];
        #pragma unroll
        for (int i = 0; i < 4; ++i) {
            #pragma unroll
            for (int rr = 0; rr < 4; ++rr) {
                const int row = r0 + i * 16 + rr;
                const float v = acc[i][j][rr] + bv;
                if constexpr (OUT_F32) ((float*)ga.C[z])[(size_t)row * N + col] = v;
                else                   ((u16*)ga.C[z])[(size_t)row * N + col] = f2bf_rne(v);
            }
        }
    }
    (void)M;
}

// ---------------- attention over head axis, per (b, g=l/16) tile ----------------
// Q[b,l,h,d] = QL[b, h*256+g, t*64+d], l = g*16+t   (faithful to reference reshape)
__global__ __launch_bounds__(256, 2)
void attn(const u16* __restrict__ QL, const u16* __restrict__ KL, const u16* __restrict__ VL,
          u16* __restrict__ CTX, float* __restrict__ WOUT) {
    __shared__ u16 Ks[16 * 1024];
    __shared__ u16 Vs[16 * 1024];
    const int bg = blockIdx.x;
    const int b = bg >> 8, g = bg & 255;
    const int tid = threadIdx.x, lane = tid & 63, wave = tid >> 6;
    const size_t boff = (size_t)b * (4096 * 1024);

    for (int it = 0; it < 8; ++it) {
        const int c = it * 4 + wave;           // 0..31
        const int row = c >> 1, half = c & 1;
        const size_t gidx = boff + (size_t)(row * 256 + g) * 1024 + half * 512 + lane * 8;
        gl_lds16(KL + gidx, &Ks[c * 512]);
        gl_lds16(VL + gidx, &Vs[c * 512]);
    }
    __syncthreads();

    const int t = tid >> 4, h = tid & 15;
    float qf[64];
    const u16* qp = QL + boff + (size_t)(h * 256 + g) * 1024 + t * 64;
    #pragma unroll
    for (int c8 = 0; c8 < 8; ++c8) {
        uint4 u = *(const uint4*)(qp + c8 * 8);
        unpack8(u, &qf[c8 * 8]);
    }
    float s[16];
    #pragma unroll 1
    for (int j = 0; j < 16; ++j) {
        const u16* kp = &Ks[j * 1024 + t * 64];
        float a = 0.f;
        #pragma unroll
        for (int c8 = 0; c8 < 8; ++c8) {
            uint4 u = *(const uint4*)(kp + c8 * 8);
            float kf[8]; unpack8(u, kf);
            #pragma unroll
            for (int d = 0; d < 8; ++d) a = fmaf(qf[c8 * 8 + d], kf[d], a);
        }
        s[j] = a * 0.125f;
    }
    float mx = s[0];
    #pragma unroll
    for (int j = 1; j < 16; ++j) mx = fmaxf(mx, s[j]);
    float w[16], sum = 0.f;
    #pragma unroll
    for (int j = 0; j < 16; ++j) { w[j] = __expf(s[j] - mx); sum += w[j]; }
    const float inv = 1.f / sum;
    #pragma unroll
    for (int j = 0; j < 16; ++j) w[j] *= inv;
    {
        float4* wp = (float4*)(WOUT + ((size_t)((b * 4096 + g * 16 + t) * 16 + h) * 16));
        wp[0] = float4{w[0],  w[1],  w[2],  w[3]};
        wp[1] = float4{w[4],  w[5],  w[6],  w[7]};
        wp[2] = float4{w[8],  w[9],  w[10], w[11]};
        wp[3] = float4{w[12], w[13], w[14], w[15]};
    }
    float cx[64];
    #pragma unroll
    for (int d = 0; d < 64; ++d) cx[d] = 0.f;
    #pragma unroll 1
    for (int j = 0; j < 16; ++j) {
        const u16* vp = &Vs[j * 1024 + t * 64];
        const float wj = w[j];
        #pragma unroll
        for (int c8 = 0; c8 < 8; ++c8) {
            uint4 u = *(const uint4*)(vp + c8 * 8);
            float vf[8]; unpack8(u, vf);
            #pragma unroll
            for (int d = 0; d < 8; ++d) cx[c8 * 8 + d] = fmaf(wj, vf[d], cx[c8 * 8 + d]);
        }
    }
    u16* cp = CTX + boff + (size_t)(h * 256 + g) * 1024 + t * 64;
    #pragma unroll
    for (int c8 = 0; c8 < 8; ++c8) {
        uint4 o;
        o.x = pk_bf2(cx[c8 * 8 + 0], cx[c8 * 8 + 1]);
        o.y = pk_bf2(cx[c8 * 8 + 2], cx[c8 * 8 + 3]);
        o.z = pk_bf2(cx[c8 * 8 + 4], cx[c8 * 8 + 5]);
        o.w = pk_bf2(cx[c8 * 8 + 6], cx[c8 * 8 + 7]);
        *(uint4*)(cp + c8 * 8) = o;
    }
}

// ---------------- host ----------------
extern "C" void kernel_launch(void* const* d_in, const int* in_sizes, int n_in,
                              void* d_out, int out_size, void* d_ws, size_t ws_size,
                              hipStream_t stream) {
    const float* q  = (const float*)d_in[0];
    const float* k  = (const float*)d_in[1];
    const float* v  = (const float*)d_in[2];
    const float* Wq = (const float*)d_in[3];
    const float* bq = (const float*)d_in[4];
    const float* Wk = (const float*)d_in[5];
    const float* bk = (const float*)d_in[6];
    const float* Wv = (const float*)d_in[7];
    const float* bv = (const float*)d_in[8];
    const float* Wo = (const float*)d_in[9];
    const float* bo = (const float*)d_in[10];

    const int M = 32768, D = 1024;
    const size_t MD = (size_t)M * D;
    const int n8 = (int)(MD / 8);

    u16* WT0 = (u16*)d_ws;
    u16* WT1 = WT0 + 1048576;
    u16* WT2 = WT1 + 1048576;
    u16* WT3 = WT2 + 1048576;
    u16* big0 = WT3 + 1048576;

    float* out  = (float*)d_out;
    float* wout = out + MD;

    WtArgs wa{{Wq, Wk, Wv, Wo}, {WT0, WT1, WT2, WT3}};
    wtrans<<<dim3(16, 16, 4), 256, 0, stream>>>(wa);

    const size_t needBig = 2ull * (4ull * 1048576 + 6ull * MD);   // ~392 MiB
    if (ws_size >= needBig) {
        // fused path: 3 bf16 input copies live at once, single QKV GEMM launch
        u16* QB = big0;      u16* KB = QB + MD;  u16* VB = KB + MD;
        u16* QL = VB + MD;   u16* KL = QL + MD;  u16* VL = KL + MD;
        u16* CTX = QB;       // QB dead after GEMM1
        CvtArgs ca{{q, k, v}, {QB, KB, VB}};
        cvt3<<<dim3(1024, 3), 256, 0, stream>>>(ca, n8);
        GemmArgs g1{{QB, KB, VB}, {WT0, WT1, WT2}, {bq, bk, bv}, {QL, KL, VL}};
        gemm_bt<false><<<dim3(3 * 2048), 256, 0, stream>>>(g1, M, D, D);
        attn<<<dim3(2048), 256, 0, stream>>>(QL, KL, VL, CTX, wout);
        GemmArgs g2{{CTX, CTX, CTX}, {WT3, WT3, WT3}, {bo, bo, bo}, {out, out, out}};
        gemm_bt<true><<<dim3(2048), 256, 0, stream>>>(g2, M, D, D);
    } else {
        // conservative path: one shared bf16 A-buffer (264 MiB footprint)
        u16* AB = big0;
        u16* QL = AB + MD;   u16* KL = QL + MD;  u16* VL = KL + MD;
        u16* CTX = AB;       // AB dead after the three GEMM1s
        const float* src[3]  = {q, k, v};
        const float* bia[3]  = {bq, bk, bv};
        u16* wt[3]           = {WT0, WT1, WT2};
        u16* dst[3]          = {QL, KL, VL};
        for (int i = 0; i < 3; ++i) {
            CvtArgs ca{{src[i], src[i], src[i]}, {AB, AB, AB}};
            cvt3<<<dim3(1024, 1), 256, 0, stream>>>(ca, n8);
            GemmArgs g1{{AB, AB, AB}, {wt[i], wt[i], wt[i]}, {bia[i], bia[i], bia[i]},
                        {dst[i], dst[i], dst[i]}};
            gemm_bt<false><<<dim3(2048), 256, 0, stream>>>(g1, M, D, D);
        }
        attn<<<dim3(2048), 256, 0, stream>>>(QL, KL, VL, CTX, wout);
        GemmArgs g2{{CTX, CTX, CTX}, {WT3, WT3, WT3}, {bo, bo, bo}, {out, out, out}};
        gemm_bt<true><<<dim3(2048), 256, 0, stream>>>(g2, M, D, D);
    }
}

// Round 4
// 860.749 us; speedup vs baseline: 1.4989x; 1.0524x over previous
//
#include <hip/hip_runtime.h>
#include <hip/hip_bf16.h>
#include <stdint.h>

typedef unsigned short u16;
typedef unsigned int   u32;
typedef __attribute__((ext_vector_type(8))) short bf16x8;
typedef __attribute__((ext_vector_type(4))) float f32x4;

#define GLAS  __attribute__((address_space(1)))
#define LDSAS __attribute__((address_space(3)))

// async global->LDS, 16B per lane. LDS dest is wave-uniform base + lane*16.
__device__ __forceinline__ void gl_lds16(const void* g, void* l) {
    __builtin_amdgcn_global_load_lds((const GLAS u32*)(uintptr_t)g,
                                     (LDSAS u32*)(u32)(uintptr_t)l, 16, 0, 0);
}

// RNE fp32->bf16
__device__ __forceinline__ u16 f2bf_rne(float f) {
    u32 u = __float_as_uint(f);
    u32 r = u + 0x7fffu + ((u >> 16) & 1u);
    return (u16)(r >> 16);
}
// packed pair (v_cvt_pk_bf16_f32 on gfx950), low16 = a
__device__ __forceinline__ u32 pk_bf2(float a, float b) {
    __hip_bfloat162 h = __float22bfloat162_rn(float2{a, b});
    u32 u; __builtin_memcpy(&u, &h, 4);
    return u;
}
__device__ __forceinline__ float bfbits_lo(u32 p) { return __uint_as_float(p << 16); }
__device__ __forceinline__ float bfbits_hi(u32 p) { return __uint_as_float(p & 0xffff0000u); }

__device__ __forceinline__ void unpack8(uint4 u, float* f) {
    f[0] = bfbits_lo(u.x); f[1] = bfbits_hi(u.x);
    f[2] = bfbits_lo(u.y); f[3] = bfbits_hi(u.y);
    f[4] = bfbits_lo(u.z); f[5] = bfbits_hi(u.z);
    f[6] = bfbits_lo(u.w); f[7] = bfbits_hi(u.w);
}

// ---------------- weight transpose + convert: WT[n][k] = bf16(W[k][n]) ----------------
struct WtArgs { const float* W[4]; u16* WT[4]; };

__global__ __launch_bounds__(256) void wtrans(WtArgs a) {
    const int z = blockIdx.z;
    const float* __restrict__ W = a.W[z];
    u16* __restrict__ WT = a.WT[z];
    __shared__ float tile[64][65];
    const int n0 = blockIdx.x * 64, k0 = blockIdx.y * 64;
    const int tid = threadIdx.x;
    const int r = tid >> 6, c = tid & 63;
    #pragma unroll
    for (int p = 0; p < 16; ++p) {
        const int row = p * 4 + r;
        tile[row][c] = W[(size_t)(k0 + row) * 1024 + n0 + c];
    }
    __syncthreads();
    #pragma unroll
    for (int p = 0; p < 16; ++p) {
        const int row = p * 4 + r;   // n index within tile
        WT[(size_t)(n0 + row) * 1024 + k0 + c] = f2bf_rne(tile[c][row]);
    }
}

// ---------------- fp32 -> bf16 streaming convert (up to 3 tensors per launch) --------
struct CvtArgs { const float* src[3]; u16* dst[3]; };

__global__ __launch_bounds__(256) void cvt3(CvtArgs a, int n8) {
    const int z = blockIdx.y;
    const float* __restrict__ src = a.src[z];
    u16* __restrict__ dst = a.dst[z];
    const int stride = gridDim.x * 256;
    for (int i = blockIdx.x * 256 + threadIdx.x; i < n8; i += stride) {
        const float4* s = (const float4*)(src + (size_t)i * 8);
        float4 x = s[0], y = s[1];
        uint4 o;
        o.x = pk_bf2(x.x, x.y); o.y = pk_bf2(x.z, x.w);
        o.z = pk_bf2(y.x, y.y); o.w = pk_bf2(y.z, y.w);
        *(uint4*)(dst + (size_t)i * 8) = o;
    }
}

// ---------------- GEMM: C[m][n] = sum_k A[m][k] * BT[n][k] + bias[n] ----------------
// m97 2-barrier structure, 128x128 tile, BK=64 (half the barrier drains of BK=32).
// LDS tiles are [128][64] u16 (128 B rows) with XOR swizzle byte^=(row&7)<<4:
//   - global_load_lds dest stays LINEAR; the swizzle is applied by permuting the
//     SOURCE column per lane (col = ((l&7)^(l>>3))*8), rule-21 both-sides pattern.
//   - ds_read side applies the same XOR -> 16 fr-lanes spread over 8 16B slots
//     (2-way aliasing only, free per m136).
struct GemmArgs { const u16* A[3]; const u16* BT[3]; const float* bias[3]; void* C[3]; };

template<bool OUT_F32>
__global__ __launch_bounds__(256, 2)
void gemm_bt(GemmArgs ga, int M, int N, int K) {
    __shared__ u16 As[128 * 64];
    __shared__ u16 Bs[128 * 64];
    const int L = blockIdx.x;
    const int z = L >> 11;               // 2048 blocks per z
    const int r = L & 2047;
    const int xcd = r & 7;
    const int slot = r >> 3;             // 0..255 within partition
    const int m0 = (xcd * 32 + (slot >> 3)) * 128;
    const int n0 = (slot & 7) * 128;

    const u16*   __restrict__ A    = ga.A[z];
    const u16*   __restrict__ BT   = ga.BT[z];
    const float* __restrict__ bias = ga.bias[z];
    const int tid = threadIdx.x;
    const int lane = tid & 63;
    const int wave = tid >> 6;

    f32x4 acc[4][4] = {};

    const int srow = lane >> 3;                     // 0..7 within 8-row chunk
    const int scol = ((lane & 7) ^ srow) * 8;       // pre-swizzled source col (u16)

    const int wm = (wave >> 1) * 64;
    const int wn = (wave & 1) * 64;
    const int fr = lane & 15;
    const int fk = (lane >> 4) * 8;
    const int fx = (fr & 7) << 3;                   // read-side XOR (u16 units)

    for (int k0 = 0; k0 < K; k0 += 64) {
        // ---- stage A and B tiles (128x64 bf16 each) via async global->LDS
        #pragma unroll
        for (int cc = 0; cc < 4; ++cc) {
            const int chunk = cc * 4 + wave;        // 0..15, 8 rows each
            gl_lds16(A  + (size_t)(m0 + chunk * 8 + srow) * K + (k0 + scol),
                     &As[chunk * 512]);
            gl_lds16(BT + (size_t)(n0 + chunk * 8 + srow) * K + (k0 + scol),
                     &Bs[chunk * 512]);
        }
        __syncthreads();

        // ---- fragments + MFMA (2 k-subtiles of 32)
        bf16x8 af[4][2], bfr[4][2];
        #pragma unroll
        for (int i = 0; i < 4; ++i) {
            const int rowb = (wm + i * 16 + fr) * 64;
            af[i][0] = *(const bf16x8*)&As[rowb + ((0 * 32 + fk) ^ fx)];
            af[i][1] = *(const bf16x8*)&As[rowb + ((1 * 32 + fk) ^ fx)];
        }
        #pragma unroll
        for (int j = 0; j < 4; ++j) {
            const int rowb = (wn + j * 16 + fr) * 64;
            bfr[j][0] = *(const bf16x8*)&Bs[rowb + ((0 * 32 + fk) ^ fx)];
            bfr[j][1] = *(const bf16x8*)&Bs[rowb + ((1 * 32 + fk) ^ fx)];
        }
        #pragma unroll
        for (int kk = 0; kk < 2; ++kk)
            #pragma unroll
            for (int i = 0; i < 4; ++i)
                #pragma unroll
                for (int j = 0; j < 4; ++j)
                    acc[i][j] = __builtin_amdgcn_mfma_f32_16x16x32_bf16(
                        af[i][kk], bfr[j][kk], acc[i][j], 0, 0, 0);
        __syncthreads();
    }

    // ---- epilogue: C/D layout col=lane&15, row=(lane>>4)*4+rr
    const int r0 = m0 + wm + (lane >> 4) * 4;
    const int c0 = n0 + wn + (lane & 15);
    #pragma unroll
    for (int j = 0; j < 4; ++j) {
        const int col = c0 + j * 16;
        const float bv = bias[col];
        #pragma unroll
        for (int i = 0; i < 4; ++i) {
            #pragma unroll
            for (int rr = 0; rr < 4; ++rr) {
                const int row = r0 + i * 16 + rr;
                const float v = acc[i][j][rr] + bv;
                if constexpr (OUT_F32) ((float*)ga.C[z])[(size_t)row * N + col] = v;
                else                   ((u16*)ga.C[z])[(size_t)row * N + col] = f2bf_rne(v);
            }
        }
    }
    (void)M;
}

// ---------------- attention over head axis, per (b, g=l/16) tile ----------------
// Q[b,l,h,d] = QL[b, h*256+g, t*64+d], l = g*16+t   (faithful to reference reshape)
// 512 threads: h = tid&15, dh = (tid>>4)&1 (d-half), t = tid>>5.
// Each thread handles a 32-wide d-half; the QK dot is completed via shfl_xor(16).
// Single 32 KB LDS buffer staged K-then-V (phased) -> 2 blocks/CU, ~4 waves/SIMD.
__global__ __launch_bounds__(512, 4)
void attn(const u16* __restrict__ QL, const u16* __restrict__ KL, const u16* __restrict__ VL,
          u16* __restrict__ CTX, float* __restrict__ WOUT) {
    __shared__ u16 KVs[16 * 1024];
    const int bg = blockIdx.x;
    const int b = bg >> 8, g = bg & 255;
    const int tid = threadIdx.x, lane = tid & 63, wave = tid >> 6;
    const size_t boff = (size_t)b * (4096 * 1024);

    // ---- stage K (16 rows x 1024 u16 = 32 KB, 32 chunks of 1 KB, 4 per wave)
    #pragma unroll
    for (int it = 0; it < 4; ++it) {
        const int c = it * 8 + wave;           // 0..31
        const int row = c >> 1, half = c & 1;
        const size_t gidx = boff + (size_t)(row * 256 + g) * 1024 + half * 512 + lane * 8;
        gl_lds16(KL + gidx, &KVs[c * 512]);
    }

    const int h = tid & 15, dh = (tid >> 4) & 1, t = tid >> 5;
    const int dof = t * 64 + dh * 32;

    // ---- Q half-row into registers (overlaps the K DMA)
    float qf[32];
    const u16* qp = QL + boff + (size_t)(h * 256 + g) * 1024 + dof;
    #pragma unroll
    for (int c4 = 0; c4 < 4; ++c4) {
        uint4 u = *(const uint4*)(qp + c4 * 8);
        unpack8(u, &qf[c4 * 8]);
    }
    __syncthreads();   // K in LDS, Q in regs

    // ---- scores over heads j (partial over 32 d, completed via shfl pair)
    float w[16];
    #pragma unroll 1
    for (int j = 0; j < 16; ++j) {
        const u16* kp = &KVs[j * 1024 + dof];
        float a = 0.f;
        #pragma unroll
        for (int c4 = 0; c4 < 4; ++c4) {
            uint4 u = *(const uint4*)(kp + c4 * 8);
            float kf[8]; unpack8(u, kf);
            #pragma unroll
            for (int d = 0; d < 8; ++d) a = fmaf(qf[c4 * 8 + d], kf[d], a);
        }
        a += __shfl_xor(a, 16);
        w[j] = a * 0.125f;   // hd^-0.5 = 1/8
    }
    // ---- softmax over j (replicated in both dh lanes; identical values)
    float mx = w[0];
    #pragma unroll
    for (int j = 1; j < 16; ++j) mx = fmaxf(mx, w[j]);
    float sum = 0.f;
    #pragma unroll
    for (int j = 0; j < 16; ++j) { w[j] = __expf(w[j] - mx); sum += w[j]; }
    const float inv = 1.f / sum;
    #pragma unroll
    for (int j = 0; j < 16; ++j) w[j] *= inv;

    __syncthreads();   // all K reads done -> buffer reusable

    // ---- stage V into the same buffer
    #pragma unroll
    for (int it = 0; it < 4; ++it) {
        const int c = it * 8 + wave;
        const int row = c >> 1, half = c & 1;
        const size_t gidx = boff + (size_t)(row * 256 + g) * 1024 + half * 512 + lane * 8;
        gl_lds16(VL + gidx, &KVs[c * 512]);
    }
    __syncthreads();   // V in LDS

    // ---- ctx = sum_j w[j] * V[j] (32-d half per thread)
    float cx[32];
    #pragma unroll
    for (int d = 0; d < 32; ++d) cx[d] = 0.f;
    #pragma unroll 1
    for (int j = 0; j < 16; ++j) {
        const u16* vp = &KVs[j * 1024 + dof];
        const float wj = w[j];
        #pragma unroll
        for (int c4 = 0; c4 < 4; ++c4) {
            uint4 u = *(const uint4*)(vp + c4 * 8);
            float vf[8]; unpack8(u, vf);
            #pragma unroll
            for (int d = 0; d < 8; ++d) cx[c4 * 8 + d] = fmaf(wj, vf[d], cx[c4 * 8 + d]);
        }
    }
    // ---- write ctx_merged[b, h*256+g, t*64+dh*32+d] as bf16
    u16* cp = CTX + boff + (size_t)(h * 256 + g) * 1024 + dof;
    #pragma unroll
    for (int c4 = 0; c4 < 4; ++c4) {
        uint4 o;
        o.x = pk_bf2(cx[c4 * 8 + 0], cx[c4 * 8 + 1]);
        o.y = pk_bf2(cx[c4 * 8 + 2], cx[c4 * 8 + 3]);
        o.z = pk_bf2(cx[c4 * 8 + 4], cx[c4 * 8 + 5]);
        o.w = pk_bf2(cx[c4 * 8 + 6], cx[c4 * 8 + 7]);
        *(uint4*)(cp + c4 * 8) = o;
    }
    // ---- weights[b, l, h, j] (dh==0 lanes only; w identical in both halves)
    if (dh == 0) {
        float4* wp = (float4*)(WOUT + ((size_t)((b * 4096 + g * 16 + t) * 16 + h) * 16));
        wp[0] = float4{w[0],  w[1],  w[2],  w[3]};
        wp[1] = float4{w[4],  w[5],  w[6],  w[7]};
        wp[2] = float4{w[8],  w[9],  w[10], w[11]};
        wp[3] = float4{w[12], w[13], w[14], w[15]};
    }
}

// ---------------- host ----------------
extern "C" void kernel_launch(void* const* d_in, const int* in_sizes, int n_in,
                              void* d_out, int out_size, void* d_ws, size_t ws_size,
                              hipStream_t stream) {
    const float* q  = (const float*)d_in[0];
    const float* k  = (const float*)d_in[1];
    const float* v  = (const float*)d_in[2];
    const float* Wq = (const float*)d_in[3];
    const float* bq = (const float*)d_in[4];
    const float* Wk = (const float*)d_in[5];
    const float* bk = (const float*)d_in[6];
    const float* Wv = (const float*)d_in[7];
    const float* bv = (const float*)d_in[8];
    const float* Wo = (const float*)d_in[9];
    const float* bo = (const float*)d_in[10];

    const int M = 32768, D = 1024;
    const size_t MD = (size_t)M * D;
    const int n8 = (int)(MD / 8);

    u16* WT0 = (u16*)d_ws;
    u16* WT1 = WT0 + 1048576;
    u16* WT2 = WT1 + 1048576;
    u16* WT3 = WT2 + 1048576;
    u16* big0 = WT3 + 1048576;

    float* out  = (float*)d_out;
    float* wout = out + MD;

    WtArgs wa{{Wq, Wk, Wv, Wo}, {WT0, WT1, WT2, WT3}};
    wtrans<<<dim3(16, 16, 4), 256, 0, stream>>>(wa);

    const size_t needBig = 2ull * (4ull * 1048576 + 6ull * MD);   // ~392 MiB
    if (ws_size >= needBig) {
        // fused path: 3 bf16 input copies live at once, single QKV GEMM launch
        u16* QB = big0;      u16* KB = QB + MD;  u16* VB = KB + MD;
        u16* QL = VB + MD;   u16* KL = QL + MD;  u16* VL = KL + MD;
        u16* CTX = QB;       // QB dead after GEMM1
        CvtArgs ca{{q, k, v}, {QB, KB, VB}};
        cvt3<<<dim3(2048, 3), 256, 0, stream>>>(ca, n8);
        GemmArgs g1{{QB, KB, VB}, {WT0, WT1, WT2}, {bq, bk, bv}, {QL, KL, VL}};
        gemm_bt<false><<<dim3(3 * 2048), 256, 0, stream>>>(g1, M, D, D);
        attn<<<dim3(2048), 512, 0, stream>>>(QL, KL, VL, CTX, wout);
        GemmArgs g2{{CTX, CTX, CTX}, {WT3, WT3, WT3}, {bo, bo, bo}, {out, out, out}};
        gemm_bt<true><<<dim3(2048), 256, 0, stream>>>(g2, M, D, D);
    } else {
        // conservative path: one shared bf16 A-buffer (264 MiB footprint)
        u16* AB = big0;
        u16* QL = AB + MD;   u16* KL = QL + MD;  u16* VL = KL + MD;
        u16* CTX = AB;       // AB dead after the three GEMM1s
        const float* src[3]  = {q, k, v};
        const float* bia[3]  = {bq, bk, bv};
        u16* wt[3]           = {WT0, WT1, WT2};
        u16* dst[3]          = {QL, KL, VL};
        for (int i = 0; i < 3; ++i) {
            CvtArgs ca{{src[i], src[i], src[i]}, {AB, AB, AB}};
            cvt3<<<dim3(2048, 1), 256, 0, stream>>>(ca, n8);
            GemmArgs g1{{AB, AB, AB}, {wt[i], wt[i], wt[i]}, {bia[i], bia[i], bia[i]},
                        {dst[i], dst[i], dst[i]}};
            gemm_bt<false><<<dim3(2048), 256, 0, stream>>>(g1, M, D, D);
        }
        attn<<<dim3(2048), 512, 0, stream>>>(QL, KL, VL, CTX, wout);
        GemmArgs g2{{CTX, CTX, CTX}, {WT3, WT3, WT3}, {bo, bo, bo}, {out, out, out}};
        gemm_bt<true><<<dim3(2048), 256, 0, stream>>>(g2, M, D, D);
    }
}